// Round 10
// baseline (210.514 us; speedup 1.0000x reference)
//
#include <hip/hip_runtime.h>
#include <stdint.h>

// Problem constants (from reference setup_inputs)
#define BB 4
#define SS 512
#define EE 64
#define VV 50257
#define KK 250              // k_val
#define NROWS (BB * SS)     // 2048
#define FCAP 512            // per-half-row-block candidate segment capacity
// STEP_SIZE = 0.1 -> multiply by 10; TEMP = 1.0 -> no-op

// MEASUREMENT ROUND: kernels byte-identical to round 9; filter_kernel is
// launched TWICE (idempotent) so dur_us = 2*F + S + gaps. Comparing with
// round 9 (F + S + gaps = 137.9) isolates F, the filter's true cost.

// Float-domain pre-filter threshold. P(N(0,1) >= 2.4) = 0.0082 -> E[206]/half-row,
// sigma ~14 -> FCAP=512 is ~21 sigma. Correctness does NOT depend on it: rows
// with <KK survivors or a segment overflow take an exact full-row fallback.
#define THRF 2.4f
#define POISON 0xFFFFFFFFu

typedef float float4n __attribute__((ext_vector_type(4)));

__device__ __forceinline__ unsigned fkey(float f) {
    // monotonic map: larger float -> larger unsigned
    unsigned u = __float_as_uint(f);
    return (u & 0x80000000u) ? ~u : (u | 0x80000000u);
}

// ---------------- kernel 1: streaming filter (UNCHANGED from round 8/9) ----------------
__global__ __launch_bounds__(256, 8)
void filter_kernel(const float* __restrict__ lg,
                   unsigned long long* __restrict__ cand,
                   unsigned* __restrict__ cnt)
{
    __shared__ unsigned long long lbuf[FCAP];
    __shared__ unsigned lcnt;
    const int bid = blockIdx.x, tid = threadIdx.x;
    const int row = bid >> 1, half = bid & 1;
    if (tid == 0) lcnt = 0u;
    __syncthreads();

    const size_t rowbase = (size_t)row * VV;
    const unsigned p  = (4u - ((unsigned)rowbase & 3u)) & 3u;  // peel to 16B align
    const unsigned F  = (VV - p) >> 2;                         // aligned float4 count
    const unsigned F0 = F >> 1;
    const float4n* rp4 = (const float4n*)(lg + rowbase + p);

    auto emit = [&](float f, unsigned col) {
        if (f >= THRF) {
            unsigned q = atomicAdd(&lcnt, 1u);
            if (q < FCAP)
                lbuf[q] = ((unsigned long long)fkey(f) << 32) | (unsigned)(~col);
        }
    };

    const unsigned lo = half ? F0 : 0u;
    const unsigned hi = half ? F  : F0;

    if (half == 0 && tid < (int)p) emit(lg[rowbase + tid], tid);   // peel scalars

    unsigned i = lo + tid;
    for (; i + 768u < hi; i += 1024u) {        // 4 loads in flight
        float4n a = __builtin_nontemporal_load(&rp4[i]);
        float4n b = __builtin_nontemporal_load(&rp4[i + 256u]);
        float4n c = __builtin_nontemporal_load(&rp4[i + 512u]);
        float4n d = __builtin_nontemporal_load(&rp4[i + 768u]);
        float t0 = fmaxf(fmaxf(a.x, a.y), a.z);
        float t1 = fmaxf(fmaxf(a.w, b.x), b.y);
        float t2 = fmaxf(fmaxf(b.z, b.w), c.x);
        float t3 = fmaxf(fmaxf(c.y, c.z), c.w);
        float t4 = fmaxf(fmaxf(d.x, d.y), d.z);
        float u0 = fmaxf(fmaxf(t0, t1), t2);
        float u1 = fmaxf(fmaxf(t3, t4), d.w);
        if (fmaxf(u0, u1) >= THRF) {
            unsigned c0 = p + 4u*i, c1 = p + 4u*(i+256u), c2 = p + 4u*(i+512u), c3 = p + 4u*(i+768u);
            emit(a.x, c0+0); emit(a.y, c0+1); emit(a.z, c0+2); emit(a.w, c0+3);
            emit(b.x, c1+0); emit(b.y, c1+1); emit(b.z, c1+2); emit(b.w, c1+3);
            emit(c.x, c2+0); emit(c.y, c2+1); emit(c.z, c2+2); emit(c.w, c2+3);
            emit(d.x, c3+0); emit(d.y, c3+1); emit(d.z, c3+2); emit(d.w, c3+3);
        }
    }
    for (; i < hi; i += 256u) {
        float4n a = __builtin_nontemporal_load(&rp4[i]);
        float m = fmaxf(fmaxf(a.x, a.y), fmaxf(a.z, a.w));
        if (m >= THRF) {
            unsigned c0 = p + 4u*i;
            emit(a.x, c0+0); emit(a.y, c0+1); emit(a.z, c0+2); emit(a.w, c0+3);
        }
    }
    if (half == 1) {                                              // tail scalars
        for (unsigned t = p + 4u * F + tid; t < VV; t += 256u) emit(lg[rowbase + t], t);
    }

    __syncthreads();
    const unsigned total = lcnt;
    const unsigned m = total > FCAP ? FCAP : total;
    for (unsigned j = tid; j < m; j += 256u)
        cand[(size_t)bid * FCAP + j] = lbuf[j];
    if (tid == 0)
        cnt[bid] = (total > FCAP) ? POISON : total;   // poison -> exact fallback
}

// ---------------- kernel 2: per-row rank-scatter + epilogue (UNCHANGED) ----------------
__global__ __launch_bounds__(256, 6)
void select_kernel(const float* __restrict__ gx,
                   const float* __restrict__ cb,
                   const float* __restrict__ W,
                   const float* __restrict__ logits,
                   const unsigned long long* __restrict__ cand,
                   const unsigned* __restrict__ cnt,
                   float* __restrict__ out0,   // filtered [B*S, K]
                   float* __restrict__ out1)   // ids as float [B*S, K]
{
    __shared__ unsigned long long cs[2048];    // 16 KB keys; fallback hist4[4096] aliases
    __shared__ unsigned chunkSum[256];
    __shared__ float gx_s[EE], cb_s[EE];
    __shared__ float sGxcb, sCbn;
    __shared__ unsigned sThreshKey, sCnt;

    const int row = blockIdx.x;
    const int tid = threadIdx.x;
    const float* rp = logits + (size_t)row * VV;

    if (tid < EE) {   // wave 0: load row scalars + block-wide dots via shuffle reduce
        float a = gx[(size_t)row * EE + tid];
        float b = cb[(size_t)row * EE + tid];
        gx_s[tid] = a; cb_s[tid] = b;
        float p1 = a * b, p2 = b * b;
        #pragma unroll
        for (int d = 32; d > 0; d >>= 1) {
            p1 += __shfl_xor(p1, d, 64);
            p2 += __shfl_xor(p2, d, 64);
        }
        if (tid == 0) { sGxcb = p1; sCbn = p2; }
    }
    if (tid == 0) sCnt = 0u;

    const unsigned c0 = cnt[2 * row], c1 = cnt[2 * row + 1];
    const bool segs_ok = (c0 <= FCAP) && (c1 <= FCAP);
    const unsigned n = segs_ok ? c0 + c1 : 0u;

    // epilogue helper: proposal value for candidate key ck at output slot r
    auto write_out = [&](unsigned long long ck, unsigned r) {
        unsigned v = ~((unsigned)ck);
        const float4* Wv = (const float4*)(W + (size_t)v * EE);
        float d1 = 0.f, d2 = 0.f, wn = 0.f;
        #pragma unroll
        for (int j2 = 0; j2 < 16; ++j2) {
            float4 w = Wv[j2];
            float a0 = gx_s[4*j2+0], a1 = gx_s[4*j2+1], a2 = gx_s[4*j2+2], a3 = gx_s[4*j2+3];
            float b0 = cb_s[4*j2+0], b1 = cb_s[4*j2+1], b2 = cb_s[4*j2+2], b3 = cb_s[4*j2+3];
            d1 += a0*w.x + a1*w.y + a2*w.z + a3*w.w;
            d2 += b0*w.x + b1*w.y + b2*w.z + b3*w.w;
            wn += w.x*w.x + w.y*w.y + w.z*w.z + w.w*w.w;
        }
        // dist = 0.5*(t1_1 - t1_2) + (t2_1 - 2*t2_2 + t2_3)/0.1 ; out = -dist / TEMP
        float unf = -(0.5f * (d1 - sGxcb) + (wn - 2.0f * d2 + sCbn) * 10.0f);
        out0[(size_t)row * KK + r] = unf;
        out1[(size_t)row * KK + r] = (float)v;
    };

    if (segs_ok && n >= KK) {
        // ================= FAST PATH: O(n^2) rank-scatter, 1 barrier =================
        for (unsigned i = tid; i < c0; i += 256)
            cs[i] = cand[(size_t)(2 * row) * FCAP + i];
        for (unsigned i = tid; i < c1; i += 256)
            cs[c0 + i] = cand[(size_t)(2 * row + 1) * FCAP + i];
        const unsigned P4 = (n + 3u) & ~3u;          // pad to x4 for unrolled scan
        for (unsigned i = n + tid; i < P4; i += 256) cs[i] = 0ull;
        __syncthreads();

        // up to 4 candidates per thread (n <= 1024); key 0 for inactive slots
        unsigned long long k0 = (tid        < n) ? cs[tid]        : 0ull;
        unsigned long long k1 = (tid + 256u < n) ? cs[tid + 256u] : 0ull;
        unsigned long long k2 = (tid + 512u < n) ? cs[tid + 512u] : 0ull;
        unsigned long long k3 = (tid + 768u < n) ? cs[tid + 768u] : 0ull;
        unsigned r0 = 0, r1 = 0, r2 = 0, r3 = 0;
        for (unsigned j = 0; j < P4; j += 4) {       // broadcast reads, conflict-free
            unsigned long long a = cs[j], b = cs[j+1], c = cs[j+2], d = cs[j+3];
            r0 += (a > k0) + (b > k0) + (c > k0) + (d > k0);
            r1 += (a > k1) + (b > k1) + (c > k1) + (d > k1);
            r2 += (a > k2) + (b > k2) + (c > k2) + (d > k2);
            r3 += (a > k3) + (b > k3) + (c > k3) + (d > k3);
        }
        // keys unique -> ranks are a permutation of 0..n-1; exactly KK land < KK
        if (tid        < n && r0 < KK) write_out(k0, r0);
        if (tid + 256u < n && r1 < KK) write_out(k1, r1);
        if (tid + 512u < n && r2 < KK) write_out(k2, r2);
        if (tid + 768u < n && r3 < KK) write_out(k3, r3);
        return;
    }

    // ====== EXACT FALLBACK: full-row rescan + bitonic (never taken on N(0,1)) ======
    {
        unsigned* hist4 = (unsigned*)cs;       // 4096 bins alias cs (16 KB)
        for (int i = tid; i < 4096; i += 256) hist4[i] = 0u;
        __syncthreads();

        const unsigned p  = (4u - ((unsigned)((size_t)row * VV) & 3u)) & 3u;
        const unsigned nb = (VV - p) >> 2;
        const unsigned tail0 = p + nb * 4u;
        const float4n* rp4 = (const float4n*)(rp + p);

        if (tid < (int)p) atomicAdd(&hist4[fkey(rp[tid]) >> 20], 1u);
        for (unsigned i = tid; i < nb; i += 256) {
            float4n v = rp4[i];
            atomicAdd(&hist4[fkey(v.x) >> 20], 1u);
            atomicAdd(&hist4[fkey(v.y) >> 20], 1u);
            atomicAdd(&hist4[fkey(v.z) >> 20], 1u);
            atomicAdd(&hist4[fkey(v.w) >> 20], 1u);
        }
        for (unsigned t = tail0 + tid; t < VV; t += 256) atomicAdd(&hist4[fkey(rp[t]) >> 20], 1u);
        __syncthreads();

        {
            unsigned csum = 0;
            #pragma unroll
            for (int b = 0; b < 16; ++b) csum += hist4[tid * 16 + b];
            chunkSum[tid] = csum;
        }
        __syncthreads();
        {
            unsigned g = 0;
            for (int u = tid + 1; u < 256; ++u) g += chunkSum[u];
            unsigned csm = chunkSum[tid];
            if (g < KK && g + csm >= KK) {
                unsigned cum = g;
                #pragma unroll
                for (int b = 15; b >= 0; --b) {
                    unsigned c = hist4[tid * 16 + b];
                    if (cum + c >= KK) { sThreshKey = ((unsigned)(tid * 16 + b)) << 20; break; }
                    cum += c;
                }
            }
        }
        __syncthreads();
        const unsigned keyT = sThreshKey;
        __syncthreads();   // hist4 aliases cs -> drain before collection writes

        auto emit2 = [&](unsigned k, unsigned idx) {
            if (k >= keyT) {
                unsigned q = atomicAdd(&sCnt, 1u);
                if (q < 2048) cs[q] = ((unsigned long long)k << 32) | (unsigned)(~idx);
            }
        };
        if (tid < (int)p) emit2(fkey(rp[tid]), tid);
        for (unsigned i = tid; i < nb; i += 256) {
            float4n v = rp4[i];
            unsigned ia = p + 4u * i;
            emit2(fkey(v.x), ia + 0); emit2(fkey(v.y), ia + 1);
            emit2(fkey(v.z), ia + 2); emit2(fkey(v.w), ia + 3);
        }
        for (unsigned t = tail0 + tid; t < VV; t += 256) emit2(fkey(rp[t]), t);
        __syncthreads();
        unsigned n1 = sCnt; if (n1 > 2048) n1 = 2048;
        unsigned P = 256; while (P < n1) P <<= 1;
        for (unsigned i = n1 + tid; i < P; i += 256) cs[i] = 0ull;
        __syncthreads();

        for (unsigned k = 2; k <= P; k <<= 1) {
            for (unsigned jj = k >> 1; jj > 0; jj >>= 1) {
                for (unsigned i2 = tid; i2 < P; i2 += 256) {
                    unsigned l = i2 ^ jj;
                    if (l > i2) {
                        unsigned long long a = cs[i2], b = cs[l];
                        bool up = ((i2 & k) == 0);
                        if (up ? (a < b) : (a > b)) { cs[i2] = b; cs[l] = a; }
                    }
                }
                __syncthreads();
            }
        }
        if (tid < KK) write_out(cs[tid], (unsigned)tid);
    }
}

extern "C" void kernel_launch(void* const* d_in, const int* in_sizes, int n_in,
                              void* d_out, int out_size, void* d_ws, size_t ws_size,
                              hipStream_t stream) {
    const float* gx = (const float*)d_in[0];      // [B,S,E]
    const float* cb = (const float*)d_in[1];      // [B,S,E]
    const float* W  = (const float*)d_in[2];      // [V,E]
    const float* lg = (const float*)d_in[3];      // [B,S,V]
    float* out0 = (float*)d_out;                       // filtered, 512000 floats
    float* out1 = out0 + (size_t)BB * SS * KK;         // ids as float, 512000

    // d_ws layout: cnt[4096] u32 (32 KB pad) ; cand[4096][FCAP] u64 (16.8 MB)
    unsigned* cnt = (unsigned*)d_ws;
    unsigned long long* cand = (unsigned long long*)((char*)d_ws + 32768);

    // MEASUREMENT: filter launched twice (idempotent, deterministic).
    // dur_us = 2*F + S + gaps; round-9 baseline = F + S + gaps = 137.9.
    hipLaunchKernelGGL(filter_kernel, dim3(2 * NROWS), dim3(256), 0, stream,
                       lg, cand, cnt);
    hipLaunchKernelGGL(filter_kernel, dim3(2 * NROWS), dim3(256), 0, stream,
                       lg, cand, cnt);
    hipLaunchKernelGGL(select_kernel, dim3(NROWS), dim3(256), 0, stream,
                       gx, cb, W, lg, cand, cnt, out0, out1);
}

// Round 11
// 135.247 us; speedup vs baseline: 1.5565x; 1.5565x over previous
//
#include <hip/hip_runtime.h>
#include <stdint.h>

// Problem constants (from reference setup_inputs)
#define BB 4
#define SS 512
#define EE 64
#define VV 50257
#define KK 250              // k_val
#define NROWS (BB * SS)     // 2048
#define CAP 1024            // per-row LDS candidate capacity (8 KB)
// STEP_SIZE = 0.1 -> multiply by 10; TEMP = 1.0 -> no-op

// Float-domain pre-filter threshold. P(N(0,1) >= 2.4) = 0.0082 -> E[412]/row,
// sigma ~20 -> CAP=1024 is ~30 sigma, KK=250 is ~8 sigma. Correctness does NOT
// depend on it: rows failing [KK, CAP] take the in-kernel exact fallback below.
#define THRF 2.4f

typedef float float4n __attribute__((ext_vector_type(4)));
typedef unsigned long long u64;

__device__ __forceinline__ unsigned fkey(float f) {
    // monotonic map: larger float -> larger unsigned
    unsigned u = __float_as_uint(f);
    return (u & 0x80000000u) ? ~u : (u | 0x80000000u);
}

// One block per row: stream+filter -> LDS candidates -> rank-scatter -> epilogue.
// Single dispatch; candidates never leave LDS on the fast path.
__global__ __launch_bounds__(256)
void langevin_fused(const float* __restrict__ gx,
                    const float* __restrict__ cb,
                    const float* __restrict__ W,
                    const float* __restrict__ lg,
                    float* __restrict__ out0,   // filtered [B*S, K]
                    float* __restrict__ out1)   // ids as float [B*S, K]
{
    __shared__ u64 lbuf[CAP];                  // 8 KB candidates; fallback hist aliases
    __shared__ float gx_s[EE], cb_s[EE];
    __shared__ float sGxcb, sCbn;
    __shared__ unsigned lcnt, sTbin;

    const int row = blockIdx.x;
    const int tid = threadIdx.x;
    const float* rp = lg + (size_t)row * VV;

    if (tid < EE) {   // wave 0: row scalars + block-wide dots via shuffle reduce
        float a = gx[(size_t)row * EE + tid];
        float b = cb[(size_t)row * EE + tid];
        gx_s[tid] = a; cb_s[tid] = b;
        float p1 = a * b, p2 = b * b;
        #pragma unroll
        for (int d = 32; d > 0; d >>= 1) {
            p1 += __shfl_xor(p1, d, 64);
            p2 += __shfl_xor(p2, d, 64);
        }
        if (tid == 0) { sGxcb = p1; sCbn = p2; }
    }
    if (tid == 0) lcnt = 0u;
    __syncthreads();

    const unsigned p  = (4u - ((unsigned)((size_t)row * VV) & 3u)) & 3u; // 16B-align peel
    const unsigned F  = (VV - p) >> 2;                                   // aligned float4s
    const unsigned tail0 = p + 4u * F;
    const float4n* rp4 = (const float4n*)(rp + p);

    auto emit = [&](float f, unsigned col) {
        if (f >= THRF) {
            unsigned q = atomicAdd(&lcnt, 1u);
            if (q < CAP) lbuf[q] = ((u64)fkey(f) << 32) | (unsigned)(~col);
        }
    };

    // ---- streaming filter: whole row, 4 loads in flight, 16-wide max guard ----
    if (tid < (int)p) emit(rp[tid], tid);
    unsigned i = tid;
    for (; i + 768u < F; i += 1024u) {
        float4n a = __builtin_nontemporal_load(&rp4[i]);
        float4n b = __builtin_nontemporal_load(&rp4[i + 256u]);
        float4n c = __builtin_nontemporal_load(&rp4[i + 512u]);
        float4n d = __builtin_nontemporal_load(&rp4[i + 768u]);
        float t0 = fmaxf(fmaxf(a.x, a.y), a.z);
        float t1 = fmaxf(fmaxf(a.w, b.x), b.y);
        float t2 = fmaxf(fmaxf(b.z, b.w), c.x);
        float t3 = fmaxf(fmaxf(c.y, c.z), c.w);
        float t4 = fmaxf(fmaxf(d.x, d.y), d.z);
        float u0 = fmaxf(fmaxf(t0, t1), t2);
        float u1 = fmaxf(fmaxf(t3, t4), d.w);
        if (fmaxf(u0, u1) >= THRF) {
            unsigned c0 = p + 4u*i, c1 = p + 4u*(i+256u), c2 = p + 4u*(i+512u), c3 = p + 4u*(i+768u);
            emit(a.x, c0+0); emit(a.y, c0+1); emit(a.z, c0+2); emit(a.w, c0+3);
            emit(b.x, c1+0); emit(b.y, c1+1); emit(b.z, c1+2); emit(b.w, c1+3);
            emit(c.x, c2+0); emit(c.y, c2+1); emit(c.z, c2+2); emit(c.w, c2+3);
            emit(d.x, c3+0); emit(d.y, c3+1); emit(d.z, c3+2); emit(d.w, c3+3);
        }
    }
    for (; i < F; i += 256u) {
        float4n a = __builtin_nontemporal_load(&rp4[i]);
        float m = fmaxf(fmaxf(a.x, a.y), fmaxf(a.z, a.w));
        if (m >= THRF) {
            unsigned c0 = p + 4u*i;
            emit(a.x, c0+0); emit(a.y, c0+1); emit(a.z, c0+2); emit(a.w, c0+3);
        }
    }
    for (unsigned t = tail0 + tid; t < VV; t += 256u) emit(rp[t], t);
    __syncthreads();

    unsigned n = lcnt;

    if (n < KK || n > CAP) {
        // ====== EXACT FALLBACK (never taken on N(0,1) data) ======
        // 1024-bin histogram on fkey>>22, aliasing the dead lbuf region.
        unsigned* hist = (unsigned*)lbuf;                 // 4 KB  (lbuf[0..511])
        unsigned* chunkSum = ((unsigned*)lbuf) + 1024;    // 1 KB  (lbuf[512..639])
        for (int j = tid; j < 1024; j += 256) hist[j] = 0u;
        __syncthreads();

        if (tid < (int)p) atomicAdd(&hist[fkey(rp[tid]) >> 22], 1u);
        for (unsigned j = tid; j < F; j += 256u) {
            float4n v = rp4[j];
            atomicAdd(&hist[fkey(v.x) >> 22], 1u);
            atomicAdd(&hist[fkey(v.y) >> 22], 1u);
            atomicAdd(&hist[fkey(v.z) >> 22], 1u);
            atomicAdd(&hist[fkey(v.w) >> 22], 1u);
        }
        for (unsigned t = tail0 + tid; t < VV; t += 256u) atomicAdd(&hist[fkey(rp[t]) >> 22], 1u);
        __syncthreads();

        chunkSum[tid] = hist[tid*4] + hist[tid*4+1] + hist[tid*4+2] + hist[tid*4+3];
        __syncthreads();
        {
            unsigned g = 0;
            for (int u2 = tid + 1; u2 < 256; ++u2) g += chunkSum[u2];
            unsigned csm = chunkSum[tid];
            if (g < KK && g + csm >= KK) {
                unsigned cum = g;
                #pragma unroll
                for (int b2 = 3; b2 >= 0; --b2) {
                    unsigned c2 = hist[tid*4 + b2];
                    if (cum + c2 >= KK) { sTbin = (unsigned)(tid*4 + b2); break; }
                    cum += c2;
                }
            }
        }
        __syncthreads();
        const unsigned keyT = sTbin << 22;
        if (tid == 0) lcnt = 0u;
        __syncthreads();   // hist/chunkSum dead -> lbuf reusable for collection

        auto emit2 = [&](float f, unsigned col) {
            unsigned k = fkey(f);
            if (k >= keyT) {
                unsigned q = atomicAdd(&lcnt, 1u);
                if (q < CAP) lbuf[q] = ((u64)k << 32) | (unsigned)(~col);
            }
        };
        if (tid < (int)p) emit2(rp[tid], tid);
        for (unsigned j = tid; j < F; j += 256u) {
            float4n v = rp4[j];
            unsigned ia = p + 4u*j;
            emit2(v.x, ia+0); emit2(v.y, ia+1); emit2(v.z, ia+2); emit2(v.w, ia+3);
        }
        for (unsigned t = tail0 + tid; t < VV; t += 256u) emit2(rp[t], t);
        __syncthreads();
        n = lcnt;
        if (n > CAP) n = CAP;   // pathological mass-tie truncation (same standard as prior rounds)
    }

    // ---- rank-scatter: rank_i = #{j: key_j > key_i}; unique keys -> permutation ----
    const unsigned P4 = (n + 3u) & ~3u;
    for (unsigned j = n + tid; j < P4; j += 256u) lbuf[j] = 0ull;
    __syncthreads();

    auto wout = [&](u64 ck, unsigned r) {   // epilogue: proposal value at id, slot r
        unsigned v = ~((unsigned)ck);
        const float4* Wv = (const float4*)(W + (size_t)v * EE);
        float d1 = 0.f, d2 = 0.f, wn = 0.f;
        #pragma unroll
        for (int j2 = 0; j2 < 16; ++j2) {
            float4 w = Wv[j2];
            float a0 = gx_s[4*j2+0], a1 = gx_s[4*j2+1], a2 = gx_s[4*j2+2], a3 = gx_s[4*j2+3];
            float b0 = cb_s[4*j2+0], b1 = cb_s[4*j2+1], b2 = cb_s[4*j2+2], b3 = cb_s[4*j2+3];
            d1 += a0*w.x + a1*w.y + a2*w.z + a3*w.w;
            d2 += b0*w.x + b1*w.y + b2*w.z + b3*w.w;
            wn += w.x*w.x + w.y*w.y + w.z*w.z + w.w*w.w;
        }
        // dist = 0.5*(t1_1 - t1_2) + (t2_1 - 2*t2_2 + t2_3)/0.1 ; out = -dist / TEMP
        float unf = -(0.5f * (d1 - sGxcb) + (wn - 2.0f * d2 + sCbn) * 10.0f);
        out0[(size_t)row * KK + r] = unf;
        out1[(size_t)row * KK + r] = (float)v;
    };

    u64 k0 = ((unsigned)tid < n)        ? lbuf[tid]        : 0ull;
    u64 k1 = ((unsigned)tid + 256u < n) ? lbuf[tid + 256u] : 0ull;
    unsigned r0 = 0, r1 = 0;
    if (n <= 512u) {          // block-uniform branch: typical case, 2 slots only
        for (unsigned j = 0; j < P4; j += 4) {
            u64 a = lbuf[j], b = lbuf[j+1], c = lbuf[j+2], d = lbuf[j+3];
            r0 += (a > k0) + (b > k0) + (c > k0) + (d > k0);
            r1 += (a > k1) + (b > k1) + (c > k1) + (d > k1);
        }
        if ((unsigned)tid < n        && r0 < KK) wout(k0, r0);
        if ((unsigned)tid + 256u < n && r1 < KK) wout(k1, r1);
    } else {
        u64 k2 = ((unsigned)tid + 512u < n) ? lbuf[tid + 512u] : 0ull;
        u64 k3 = ((unsigned)tid + 768u < n) ? lbuf[tid + 768u] : 0ull;
        unsigned r2 = 0, r3 = 0;
        for (unsigned j = 0; j < P4; j += 4) {
            u64 a = lbuf[j], b = lbuf[j+1], c = lbuf[j+2], d = lbuf[j+3];
            r0 += (a > k0) + (b > k0) + (c > k0) + (d > k0);
            r1 += (a > k1) + (b > k1) + (c > k1) + (d > k1);
            r2 += (a > k2) + (b > k2) + (c > k2) + (d > k2);
            r3 += (a > k3) + (b > k3) + (c > k3) + (d > k3);
        }
        if ((unsigned)tid < n        && r0 < KK) wout(k0, r0);
        if ((unsigned)tid + 256u < n && r1 < KK) wout(k1, r1);
        if ((unsigned)tid + 512u < n && r2 < KK) wout(k2, r2);
        if ((unsigned)tid + 768u < n && r3 < KK) wout(k3, r3);
    }
}

extern "C" void kernel_launch(void* const* d_in, const int* in_sizes, int n_in,
                              void* d_out, int out_size, void* d_ws, size_t ws_size,
                              hipStream_t stream) {
    const float* gx = (const float*)d_in[0];      // [B,S,E]
    const float* cb = (const float*)d_in[1];      // [B,S,E]
    const float* W  = (const float*)d_in[2];      // [V,E]
    const float* lg = (const float*)d_in[3];      // [B,S,V]
    float* out0 = (float*)d_out;                       // filtered, 512000 floats
    float* out1 = out0 + (size_t)BB * SS * KK;         // ids as float, 512000

    hipLaunchKernelGGL(langevin_fused, dim3(NROWS), dim3(256), 0, stream,
                       gx, cb, W, lg, out0, out1);
}